// Round 2
// baseline (448.104 us; speedup 1.0000x reference)
//
#include <hip/hip_runtime.h>

// out[b, l, :] = x[b, perm[b, l], :]
// B=64, L=4096, D=256 (fp32) -> 16,777,216 float4 elements total.
//
// Persistent grid (2048 blocks x 256 threads), grid-stride with 8-way
// unroll: each thread batches 8 independent {perm load -> 1KiB row load}
// chains so ~8 KiB of reads are outstanding per wave (ILP), instead of
// round-1's one-load-per-short-lived-wave latency-bound structure.

#define B_DIM   64
#define L_DIM   4096
#define D_DIM   256
#define D4      (D_DIM / 4)            // 64 float4 per row
#define TOTAL4  (B_DIM * L_DIM * D4)   // 16,777,216
#define NBLK    2048
#define NTHR    256
#define UNROLL  8

__global__ __launch_bounds__(NTHR) void gather_rows_kernel(
    const float4* __restrict__ x,
    const int*    __restrict__ perm,
    float4*       __restrict__ out)
{
    const int tid    = blockIdx.x * NTHR + threadIdx.x;   // 0 .. 524287
    const int stride = NBLK * NTHR;                       // 524288

    // TOTAL4 / (stride*UNROLL) = 4 outer iterations, no tail.
    for (int base = tid; base < TOTAL4; base += stride * UNROLL) {
        int src[UNROLL];
        // 1) issue all perm loads (independent; wave-uniform per u)
        #pragma unroll
        for (int u = 0; u < UNROLL; ++u) {
            const int e   = base + u * stride;
            const int row = e >> 6;                        // e / D4
            src[u] = perm[row];
        }
        // 2) issue all x row loads (independent 16B/lane, 1 KiB/wave each)
        float4 v[UNROLL];
        #pragma unroll
        for (int u = 0; u < UNROLL; ++u) {
            const int e    = base + u * stride;
            const int row  = e >> 6;
            const int b    = row >> 12;                    // row / L_DIM
            const int lane = e & 63;
            const long in_off = ((long)(b << 12) + (long)src[u]) * D4 + lane;
            v[u] = x[in_off];
        }
        // 3) store (sequential, coalesced)
        #pragma unroll
        for (int u = 0; u < UNROLL; ++u) {
            out[base + u * stride] = v[u];
        }
    }
}

extern "C" void kernel_launch(void* const* d_in, const int* in_sizes, int n_in,
                              void* d_out, int out_size, void* d_ws, size_t ws_size,
                              hipStream_t stream) {
    const float4* x    = (const float4*)d_in[0];
    const int*    perm = (const int*)d_in[1];
    float4*       out  = (float4*)d_out;

    gather_rows_kernel<<<NBLK, NTHR, 0, stream>>>(x, perm, out);
}

// Round 3
// 433.728 us; speedup vs baseline: 1.0331x; 1.0331x over previous
//
#include <hip/hip_runtime.h>

// out[b, l, :] = x[b, perm[b, l], :]
// B=64, L=4096, D=256 (fp32).
//
// Persistent grid: 2048 blocks x 256 thr = 8192 waves; each wave owns 32
// CONTIGUOUS output rows (32 KiB sequential store region -> good DRAM page
// locality on the write side; reads are random 1 KiB rows regardless).
// Per wave: one coalesced 128B load grabs all 32 perm entries (lanes 0..31),
// broadcast per-row via __shfl; rows processed in 4-deep batches so 4 KiB of
// row reads are in flight per wave.

#define B_DIM  64
#define L_DIM  4096
#define D4     64                 // float4 per row
#define NBLK   2048
#define NTHR   256
#define ROWS_PER_WAVE 32          // (B*L) / (NBLK*NTHR/64) = 262144/8192

__global__ __launch_bounds__(NTHR) void gather_rows_kernel(
    const float4* __restrict__ x,
    const int*    __restrict__ perm,
    float4*       __restrict__ out)
{
    const int wave  = (blockIdx.x * NTHR + threadIdx.x) >> 6;  // 0..8191
    const int lane  = threadIdx.x & 63;
    const int wbase = wave * ROWS_PER_WAVE;                    // first row
    const int b     = wbase >> 12;                             // row / L
    const long xb   = (long)b << 18;                           // b * L * D4

    // all 32 perm entries for this wave's rows, held in lanes 0..31
    const int pv = perm[wbase + (lane & 31)];

    #pragma unroll
    for (int i = 0; i < ROWS_PER_WAVE; i += 4) {
        int s[4];
        #pragma unroll
        for (int k = 0; k < 4; ++k) s[k] = __shfl(pv, i + k);

        float4 v[4];
        #pragma unroll
        for (int k = 0; k < 4; ++k)
            v[k] = x[xb + (long)s[k] * D4 + lane];

        #pragma unroll
        for (int k = 0; k < 4; ++k)
            out[(long)(wbase + i + k) * D4 + lane] = v[k];
    }
}

extern "C" void kernel_launch(void* const* d_in, const int* in_sizes, int n_in,
                              void* d_out, int out_size, void* d_ws, size_t ws_size,
                              hipStream_t stream) {
    const float4* x    = (const float4*)d_in[0];
    const int*    perm = (const int*)d_in[1];
    float4*       out  = (float4*)d_out;

    gather_rows_kernel<<<NBLK, NTHR, 0, stream>>>(x, perm, out);
}